// Round 10
// baseline (168.412 us; speedup 1.0000x reference)
//
#include <hip/hip_runtime.h>
#include <hip/hip_bf16.h>

typedef unsigned short u16;
typedef __attribute__((ext_vector_type(8))) short short8;   // 8 bf16 = 4 VGPRs
typedef __attribute__((ext_vector_type(4))) float f32x4;

#define BATCH 64
#define SEQ   256
#define CDIM  384
#define NHEAD 6
#define DHEAD 64
#define NROW  16384   // BATCH*SEQ

constexpr float SCALE = 0.051031036307982884f;  // 384^-0.5

__device__ __forceinline__ f32x4 mfma16(short8 a, short8 b, f32x4 c) {
    return __builtin_amdgcn_mfma_f32_16x16x32_bf16(a, b, c, 0, 0, 0);
}

__device__ __forceinline__ u16 f2b(float f) {
    __hip_bfloat16 h = __float2bfloat16(f);
    return *reinterpret_cast<u16*>(&h);
}

// ---------------------------------------------------------------------------
// fp32 -> bf16 conversion, 8 elems/thread.
// ---------------------------------------------------------------------------
__global__ __launch_bounds__(256) void cvt_x(
        const float* __restrict__ s, u16* __restrict__ d)
{
    const int i = (blockIdx.x * 256 + threadIdx.x) * 8;
    const float4 a = *(const float4*)(s + i);
    const float4 b = *(const float4*)(s + i + 4);
    short8 r;
    r[0] = (short)f2b(a.x); r[1] = (short)f2b(a.y);
    r[2] = (short)f2b(a.z); r[3] = (short)f2b(a.w);
    r[4] = (short)f2b(b.x); r[5] = (short)f2b(b.y);
    r[6] = (short)f2b(b.z); r[7] = (short)f2b(b.w);
    *(short8*)(d + i) = r;
}

__global__ __launch_bounds__(256) void cvt_w(
        const float* __restrict__ w0, const float* __restrict__ w1,
        const float* __restrict__ w2, const float* __restrict__ w3,
        u16* __restrict__ d0, u16* __restrict__ d1,
        u16* __restrict__ d2, u16* __restrict__ d3)
{
    const int z = blockIdx.y;
    const float* s = (z == 0) ? w0 : (z == 1) ? w1 : (z == 2) ? w2 : w3;
    u16*         d = (z == 0) ? d0 : (z == 1) ? d1 : (z == 2) ? d2 : d3;
    const int i = (blockIdx.x * 256 + threadIdx.x) * 8;
    const float4 a = *(const float4*)(s + i);
    const float4 b = *(const float4*)(s + i + 4);
    short8 r;
    r[0] = (short)f2b(a.x); r[1] = (short)f2b(a.y);
    r[2] = (short)f2b(a.z); r[3] = (short)f2b(a.w);
    r[4] = (short)f2b(b.x); r[5] = (short)f2b(b.y);
    r[6] = (short)f2b(b.z); r[7] = (short)f2b(b.w);
    *(short8*)(d + i) = r;
}

// ---------------------------------------------------------------------------
// QKV projection (all-bf16): Y = X @ W^T. 128x128 tile, BK=32, 4 waves @
// 64x64. Software-pipelined register staging (loads issued before barrier).
// grid (9, 128): bx = z*3 + n  (9 blocks sharing an x m-tile are adjacent
// in dispatch -> L2/L3 x reuse). z: 0 K->[B,H,T,D], 1 V->[B,H,D,T] (transp),
// 2 Q->[B,H,T,D].
// ---------------------------------------------------------------------------
__global__ __launch_bounds__(256) void gemm_qkv(
        const u16* __restrict__ X, const u16* __restrict__ Wk,
        const u16* __restrict__ Wv, const u16* __restrict__ Wq,
        u16* __restrict__ Kd, u16* __restrict__ VTd, u16* __restrict__ Qd)
{
    __shared__ u16 SMEM[17408];   // 34 KB: As(4096)+Bs(4096) | T(128x136)
    u16* As = SMEM;
    u16* Bs = SMEM + 4096;

    const int n0 = (blockIdx.x % 3) * 128;
    const int z  = blockIdx.x / 3;
    const int m0 = blockIdx.y * 128;
    const u16* W = (z == 0) ? Wk : (z == 1 ? Wv : Wq);

    const int tid  = threadIdx.x;
    const int lane = tid & 63;
    const int wv   = tid >> 6;
    const int l15  = lane & 15;
    const int q4   = lane >> 4;
    const int wm   = (wv >> 1) * 64;
    const int wn   = (wv & 1) * 64;

    f32x4 acc[4][4] = {};

    for (int kk = 0; kk < CDIM; kk += 32) {
        short8 areg[2], breg[2];
#pragma unroll
        for (int ch = 0; ch < 2; ++ch) {
            const int f = (ch * 256 + tid) * 8;
            const int r = f >> 5;
            const int c = f & 31;
            areg[ch] = *(const short8*)(X + (size_t)(m0 + r) * CDIM + kk + c);
            breg[ch] = *(const short8*)(W + (size_t)(n0 + r) * CDIM + kk + c);
        }
        __syncthreads();   // previous iteration's LDS readers done
#pragma unroll
        for (int ch = 0; ch < 2; ++ch) {
            const int f = (ch * 256 + tid) * 8;
            *(short8*)(As + f) = areg[ch];
            *(short8*)(Bs + f) = breg[ch];
        }
        __syncthreads();   // stores visible

        short8 af[4], bf[4];
#pragma unroll
        for (int t = 0; t < 4; ++t) {
            af[t] = *(const short8*)(As + (wm + t * 16 + l15) * 32 + q4 * 8);
            bf[t] = *(const short8*)(Bs + (wn + t * 16 + l15) * 32 + q4 * 8);
        }
#pragma unroll
        for (int tm = 0; tm < 4; ++tm)
#pragma unroll
            for (int tn = 0; tn < 4; ++tn)
                acc[tm][tn] = mfma16(af[tm], bf[tn], acc[tm][tn]);
    }

    if (z != 1) {
        // ---- scatter epilogue to [B,H,T,D] ------------------------------
        u16* D = (z == 0) ? Kd : Qd;
#pragma unroll
        for (int tm = 0; tm < 4; ++tm)
#pragma unroll
            for (int tn = 0; tn < 4; ++tn) {
                const int col = n0 + wn + tn * 16 + l15;
#pragma unroll
                for (int r = 0; r < 4; ++r) {
                    const int row = m0 + wm + tm * 16 + q4 * 4 + r;
                    const int b = row >> 8, t = row & 255;
                    const int h = col >> 6, d = col & 63;
                    D[(size_t)((b * NHEAD + h) * SEQ + t) * DHEAD + d] =
                        f2b(acc[tm][tn][r]);
                }
            }
    } else {
        // ---- transpose epilogue: V^T [B,H,D,T] --------------------------
        __syncthreads();                  // all waves done with As/Bs
        u16* T = SMEM;                    // [128 feat][136]
#pragma unroll
        for (int tm = 0; tm < 4; ++tm)
#pragma unroll
            for (int tn = 0; tn < 4; ++tn) {
                const int cl = wn + tn * 16 + l15;            // feature-local
#pragma unroll
                for (int r = 0; r < 4; ++r) {
                    const int rl = wm + tm * 16 + q4 * 4 + r; // t-local
                    T[cl * 136 + rl] = f2b(acc[tm][tn][r]);
                }
            }
        __syncthreads();
        const int b  = m0 >> 8;
        const int t0 = m0 & 255;
        const int fl = tid >> 1;          // feature-local 0..127
        const int hf = tid & 1;           // which 64-t half
        const int fg = n0 + fl;
        const int h  = fg >> 6, d = fg & 63;
        u16* dst = VTd + ((size_t)(b * NHEAD + h) * DHEAD + d) * SEQ + t0 + hf * 64;
        const u16* src = T + fl * 136 + hf * 64;
#pragma unroll
        for (int j = 0; j < 8; ++j)
            *(uint4*)(dst + j * 8) = *(const uint4*)(src + j * 8);
    }
}

// ---------------------------------------------------------------------------
// Flash-style attention: block = (chunk CH, bh). 64 q rows, causal keys
// [0, 64(CH+1)). Per 128-key phase: stage K [key][72] AND V^T [d][136]
// (one barrier), S-tile MFMAs, online-softmax update (per-phase max +
// rescale; every row has keys in phase 0 so state is always live), PV
// MFMAs, one barrier. O -> ws [B,H,T,D].
// ---------------------------------------------------------------------------
template <int CH>
__device__ __forceinline__ void attn_body(
        const u16* __restrict__ Qg, const u16* __restrict__ Kg,
        const u16* __restrict__ VTg, u16* __restrict__ Og, int bh,
        u16* Kbuf /*128x72*/, u16* Vt /*64x136*/, u16* Pbuf /*4x16x40*/)
{
    constexpr int NKEY = 64 * (CH + 1);
    constexpr int NPH  = (NKEY + 127) / 128;

    const int tid  = threadIdx.x;
    const int wv   = tid >> 6;
    const int lane = tid & 63;
    const int l15  = lane & 15;
    const int q4   = lane >> 4;
    const int qrow0 = CH * 64 + wv * 16;
    const int qmax  = qrow0 + 15;

    // Q A-frags straight from global [B,H,T,D]
    short8 aq[2];
#pragma unroll
    for (int ks = 0; ks < 2; ++ks)
        aq[ks] = *(const short8*)(Qg + (size_t)(bh * SEQ + qrow0 + l15) * DHEAD
                                     + ks * 32 + q4 * 8);

    float mrow[4], lrow[4];
#pragma unroll
    for (int r = 0; r < 4; ++r) { mrow[r] = -1e30f; lrow[r] = 0.f; }
    f32x4 o[4] = {};
    u16* Pw = Pbuf + wv * 16 * 40;

#pragma unroll
    for (int ph = 0; ph < NPH; ++ph) {
        const int rows = (NKEY - ph * 128) < 128 ? (NKEY - ph * 128) : 128;

        // ---- stage K rows and V^T rows (both coalesced) -----------------
#pragma unroll
        for (int it = 0; it < 4; ++it) {
            if (it < rows / 32) {
                const int r  = it * 32 + (tid >> 3);
                const int d0 = (tid & 7) * 8;
                *(uint4*)(Kbuf + r * 72 + d0) =
                    *(const uint4*)(Kg + (size_t)(bh * SEQ + ph * 128 + r) * DHEAD + d0);
            }
        }
        const int cpr = rows >> 3;       // uint4 chunks per d-row of Vt
#pragma unroll
        for (int it = 0; it < 4; ++it) {
            if (it < cpr / 4) {
                const int flat = it * 256 + tid;
                const int rd = flat / cpr;
                const int kc = (flat - rd * cpr) * 8;
                *(uint4*)(Vt + rd * 136 + kc) =
                    *(const uint4*)(VTg + ((size_t)bh * DHEAD + rd) * SEQ
                                        + ph * 128 + kc);
            }
        }
        __syncthreads();

        // ---- S tiles for this phase -------------------------------------
        f32x4 s[8];
        const int ntiles = rows / 16;
#pragma unroll
        for (int t = 0; t < 8; ++t) {
            if (t < ntiles) {
                const int gt = ph * 8 + t;
                if (gt * 16 <= qmax) {
                    f32x4 zz = {0.f, 0.f, 0.f, 0.f};
#pragma unroll
                    for (int ks = 0; ks < 2; ++ks) {
                        short8 bk = *(const short8*)(Kbuf + (t * 16 + l15) * 72
                                                     + ks * 32 + q4 * 8);
                        zz = mfma16(aq[ks], bk, zz);
                    }
                    const int kc = gt * 16 + l15;
#pragma unroll
                    for (int r = 0; r < 4; ++r) {
                        float v = zz[r] * SCALE;
                        if (kc > qrow0 + q4 * 4 + r) v = -1e30f;
                        zz[r] = v;
                    }
                    s[t] = zz;
                } else {
                    f32x4 neg = {-1e30f, -1e30f, -1e30f, -1e30f};
                    s[t] = neg;
                }
            }
        }

        // ---- online softmax update --------------------------------------
#pragma unroll
        for (int r = 0; r < 4; ++r) {
            float pm = -1e30f;
#pragma unroll
            for (int t = 0; t < 8; ++t)
                if (t < ntiles) pm = fmaxf(pm, s[t][r]);
#pragma unroll
            for (int off = 1; off < 16; off <<= 1)
                pm = fmaxf(pm, __shfl_xor(pm, off, 16));
            const float nm = fmaxf(mrow[r], pm);
            const float alpha = __expf(mrow[r] - nm);   // phase 0: exp(-inf)=0
            mrow[r] = nm;
            lrow[r] *= alpha;
#pragma unroll
            for (int tn = 0; tn < 4; ++tn) o[tn][r] *= alpha;
        }
#pragma unroll
        for (int t = 0; t < 8; ++t) {
            if (t < ntiles) {
#pragma unroll
                for (int r = 0; r < 4; ++r) {
                    const float p = __expf(s[t][r] - mrow[r]);
                    s[t][r] = p;
                    lrow[r] += p;      // lane-partial; reduced at the end
                }
            }
        }

        // ---- PV for this phase ------------------------------------------
#pragma unroll
        for (int ks = 0; ks < 4; ++ks) {
            if (ks < rows / 32) {
                const int gks = ph * 4 + ks;
                if (gks * 32 <= qmax) {
#pragma unroll
                    for (int tt = 0; tt < 2; ++tt) {
#pragma unroll
                        for (int r = 0; r < 4; ++r)
                            Pw[(q4 * 4 + r) * 40 + tt * 16 + l15] =
                                f2b(s[ks * 2 + tt][r]);
                    }
                    asm volatile("s_waitcnt lgkmcnt(0)" ::: "memory");
                    short8 ap = *(const short8*)(Pw + l15 * 40 + q4 * 8);
#pragma unroll
                    for (int tn = 0; tn < 4; ++tn) {
                        short8 bv = *(const short8*)(Vt + (tn * 16 + l15) * 136
                                                     + ks * 32 + q4 * 8);
                        o[tn] = mfma16(ap, bv, o[tn]);
                    }
                }
            }
        }
        if (ph + 1 < NPH) __syncthreads();   // before restaging Kbuf/Vt
    }

    // ---- finalize: reduce lane-partial sums, store ----------------------
    float rs[4];
#pragma unroll
    for (int r = 0; r < 4; ++r) {
        float l = lrow[r];
#pragma unroll
        for (int off = 1; off < 16; off <<= 1)
            l += __shfl_xor(l, off, 16);
        rs[r] = 1.f / l;
    }
#pragma unroll
    for (int tn = 0; tn < 4; ++tn) {
        const int d = tn * 16 + l15;
#pragma unroll
        for (int r = 0; r < 4; ++r) {
            const int qr = qrow0 + q4 * 4 + r;
            Og[(size_t)(bh * SEQ + qr) * DHEAD + d] = f2b(o[tn][r] * rs[r]);
        }
    }
}

__global__ __launch_bounds__(256) void attn_kernel(
        const u16* __restrict__ Qg, const u16* __restrict__ Kg,
        const u16* __restrict__ VTg, u16* __restrict__ Og)
{
    __shared__ u16 Kbuf[128 * 72];      // 18 KB
    __shared__ u16 Vt[64 * 136];        // 17 KB
    __shared__ u16 Pbuf[4 * 16 * 40];   //  5 KB
    const int bh = blockIdx.y;
    switch (blockIdx.x) {
        case 0: attn_body<0>(Qg, Kg, VTg, Og, bh, Kbuf, Vt, Pbuf); break;
        case 1: attn_body<1>(Qg, Kg, VTg, Og, bh, Kbuf, Vt, Pbuf); break;
        case 2: attn_body<2>(Qg, Kg, VTg, Og, bh, Kbuf, Vt, Pbuf); break;
        default: attn_body<3>(Qg, Kg, VTg, Og, bh, Kbuf, Vt, Pbuf); break;
    }
}

// ---------------------------------------------------------------------------
// Output projection (bf16 in, fp32 out): out = O @ Wo^T + bo. Register
// staging. O bf16 [B,H,T,D] composite read; writes fp32 [16384x384].
// ---------------------------------------------------------------------------
__global__ __launch_bounds__(256) void gemm_out(
        const u16* __restrict__ O, const u16* __restrict__ Wo,
        const float* __restrict__ bias, float* __restrict__ out)
{
    __shared__ u16 As[128 * 32];
    __shared__ u16 Bs[128 * 32];

    const int n0 = blockIdx.x * 128;
    const int m0 = blockIdx.y * 128;

    const int tid  = threadIdx.x;
    const int lane = tid & 63;
    const int wv   = tid >> 6;
    const int l15  = lane & 15;
    const int q4   = lane >> 4;
    const int wm   = (wv >> 1) * 64;
    const int wn   = (wv & 1) * 64;

    f32x4 acc[4][4] = {};

    for (int kk = 0; kk < CDIM; kk += 32) {
        uint4 areg[2];
        short8 breg[2];
#pragma unroll
        for (int ch = 0; ch < 2; ++ch) {
            const int f = (ch * 256 + tid) * 8;
            const int r = f >> 5;
            const int c = f & 31;
            const int row = m0 + r;
            const int b = row >> 8, t = row & 255;
            const int k = kk + c;
            const int hh = k >> 6, dd = k & 63;
            areg[ch] = *(const uint4*)(O +
                (size_t)((b * NHEAD + hh) * SEQ + t) * DHEAD + dd);
            breg[ch] = *(const short8*)(Wo + (size_t)(n0 + r) * CDIM + kk + c);
        }
        __syncthreads();
#pragma unroll
        for (int ch = 0; ch < 2; ++ch) {
            const int f = (ch * 256 + tid) * 8;
            *(uint4*)(As + f)  = areg[ch];
            *(short8*)(Bs + f) = breg[ch];
        }
        __syncthreads();

        short8 af[4], bf[4];
#pragma unroll
        for (int t = 0; t < 4; ++t) {
            af[t] = *(const short8*)(As + (wm + t * 16 + l15) * 32 + q4 * 8);
            bf[t] = *(const short8*)(Bs + (wn + t * 16 + l15) * 32 + q4 * 8);
        }
#pragma unroll
        for (int tm = 0; tm < 4; ++tm)
#pragma unroll
            for (int tn = 0; tn < 4; ++tn)
                acc[tm][tn] = mfma16(af[tm], bf[tn], acc[tm][tn]);
    }

#pragma unroll
    for (int tm = 0; tm < 4; ++tm) {
#pragma unroll
        for (int tn = 0; tn < 4; ++tn) {
            const int col = n0 + wn + tn * 16 + l15;
            const float bb = bias[col];
#pragma unroll
            for (int r = 0; r < 4; ++r) {
                const int row = m0 + wm + tm * 16 + q4 * 4 + r;
                out[(size_t)row * CDIM + col] = acc[tm][tn][r] + bb;  // fp32
            }
        }
    }
}

extern "C" void kernel_launch(void* const* d_in, const int* in_sizes, int n_in,
                              void* d_out, int out_size, void* d_ws, size_t ws_size,
                              hipStream_t stream)
{
    const float* x  = (const float*)d_in[0];
    const float* Wk = (const float*)d_in[1];
    const float* Wq = (const float*)d_in[2];
    const float* Wv = (const float*)d_in[3];
    const float* Wo = (const float*)d_in[4];
    const float* bo = (const float*)d_in[5];
    float* out = (float*)d_out;

    // ws layout (u16): xb + 4 weights + K + Q + O = 51.5 MB (ws ~256 MiB)
    const size_t SZ = (size_t)NROW * CDIM;   // 6,291,456
    const size_t WZ = (size_t)CDIM * CDIM;   //   147,456
    u16* xb  = (u16*)d_ws;
    u16* Wkb = xb  + SZ;
    u16* Wqb = Wkb + WZ;
    u16* Wvb = Wqb + WZ;
    u16* Wob = Wvb + WZ;
    u16* Kw  = Wob + WZ;
    u16* Qw  = Kw + SZ;
    u16* Ow  = Qw + SZ;
    u16* VTw = (u16*)d_out;   // V^T [B,H,D,T] scratch in d_out

    cvt_x<<<dim3((int)(SZ / 2048)), 256, 0, stream>>>(x, xb);
    cvt_w<<<dim3((int)(WZ / 2048), 4), 256, 0, stream>>>(
        Wk, Wq, Wv, Wo, Wkb, Wqb, Wvb, Wob);

    dim3 g1(9, NROW / 128);
    gemm_qkv<<<g1, 256, 0, stream>>>(xb, Wkb, Wvb, Wqb, Kw, VTw, Qw);

    dim3 g2(4, BATCH * NHEAD);
    attn_kernel<<<g2, 256, 0, stream>>>(Qw, Kw, VTw, Ow);

    dim3 g3(CDIM / 128, NROW / 128);
    gemm_out<<<g3, 256, 0, stream>>>(Ow, Wob, bo, out);
}